// Round 1
// baseline (84.220 us; speedup 1.0000x reference)
//
#include <hip/hip_runtime.h>
#include <math.h>

#define B_ 64
#define N_ 32
#define H_ 200
#define W_ 200
#define NSEG (N_ - 1)
#define NPIX (H_ * W_)

__global__ __launch_bounds__(256) void stroke_kernel(
    const float* __restrict__ param,      // (B, N, 3)
    const float* __restrict__ x_start,    // scalar
    const float* __restrict__ y_start,    // scalar
    const float* __restrict__ theta,      // scalar
    const float* __restrict__ weights,    // (2,2)
    const float* __restrict__ biases,     // (2,)
    const float* __restrict__ thick_mult, // scalar
    const float* __restrict__ thick_bias, // scalar
    const float* __restrict__ dark_exp_p, // scalar
    const float* __restrict__ dark_nlw_p, // scalar
    const float* __restrict__ x_m_p,      // scalar
    const float* __restrict__ y_m_p,      // scalar
    const float* __restrict__ x_b_p,      // scalar
    const float* __restrict__ y_b_p,      // scalar
    float* __restrict__ out)              // (B, H, W)
{
    __shared__ float s_vy[NSEG], s_vx[NSEG], s_wvy[NSEG], s_wvx[NSEG];
    __shared__ float s_inv_d2[NSEG], s_c0[NSEG], s_c1[NSEG];
    __shared__ float s_sy[N_], s_sx[N_], s_tk[N_];

    const int b   = blockIdx.y;
    const int tid = threadIdx.x;

    // Uniform scalars (L2-cached broadcast loads)
    const float thv  = theta[0];
    const float c    = cosf(thv), s = sinf(thv);
    const float xs   = x_start[0], ys = y_start[0];
    const float W00  = weights[0], W01 = weights[1];
    const float W10  = weights[2], W11 = weights[3];
    const float bb0  = biases[0],  bb1 = biases[1];
    const float tm   = thick_mult[0], tb = thick_bias[0];
    const float dexp = dark_exp_p[0], dnlw = dark_nlw_p[0];
    const float xm   = x_m_p[0], ym = y_m_p[0];
    const float xb   = x_b_p[0], yb = y_b_p[0];

    // Phase 1: strokes + thickness for this batch into LDS
    if (tid < N_) {
        float p0 = param[(b * N_ + tid) * 3 + 0];
        float p1 = param[(b * N_ + tid) * 3 + 1];
        float p2 = param[(b * N_ + tid) * 3 + 2];
        float x0 = p0, y0 = -p1;
        float x_rot =  x0 * c + y0 * s;
        float y_rot = -x0 * s + y0 * c;
        float yy = y_rot * ym + yb + ys;
        float xx = x_rot * xm + xb + xs;
        s_sy[tid] = yy * W00 + xx * W01 + bb0;  // pairs with coords[...,0] = gy
        s_sx[tid] = yy * W10 + xx * W11 + bb1;  // pairs with coords[...,1] = gx
        s_tk[tid] = (p2 * 2.0f + 0.5f) * (1.0f / 64.0f);
    }
    __syncthreads();

    // Phase 2: per-segment constants
    if (tid < NSEG) {
        float vy = s_sy[tid],     vx = s_sx[tid];
        float wy = s_sy[tid + 1], wx = s_sx[tid + 1];
        float wvy = wy - vy, wvx = wx - vx;
        float d2 = wvy * wvy + wvx * wvx;
        s_vy[tid] = vy;  s_vx[tid] = vx;
        s_wvy[tid] = wvy; s_wvx[tid] = wvx;
        s_inv_d2[tid] = 1.0f / (d2 + 1e-5f);
        float t0 = s_tk[tid], t1 = s_tk[tid + 1];
        s_c0[tid] = t0 * tm + tb;         // th(frac) = c0 + frac*c1
        s_c1[tid] = (t1 - t0) * tm;
    }
    __syncthreads();

    const int pix = blockIdx.x * blockDim.x + tid;
    if (pix >= NPIX) return;
    const int i = pix / W_;
    const int j = pix - i * W_;
    const float py = (float)i * (1.0f / H_);
    const float px = (float)j * (1.0f / W_);

    // pow(., dexp) and dnlw*sigmoid(16d-8)+(1-dnlw)*d are monotone-increasing
    // in d when dexp>0 and dnlw in [0,1] -> hoist transform past the max.
    const bool hoist = (dexp > 0.0f) && (dnlw >= 0.0f) && (dnlw <= 1.0f);

    float result;
    if (hoist) {
        float md = 0.0f;  // all clipped darks are >= 0
        #pragma unroll
        for (int n = 0; n < NSEG; ++n) {
            float vy = s_vy[n], vx = s_vx[n];
            float wvy = s_wvy[n], wvx = s_wvx[n];
            float dy = py - vy, dx = px - vx;
            float dot = (dy * wvy + dx * wvx) * s_inv_d2[n];
            float frac = fminf(fmaxf(dot, 0.0f), 1.0f);
            float ey = dy - frac * wvy;
            float ex = dx - frac * wvx;
            float dist = sqrtf(ey * ey + ex * ex);
            float th = fmaxf(s_c0[n] + frac * s_c1[n], 1e-8f);
            float dark = fminf(fmaxf((th - dist) / th, 0.0f), 1.0f);
            md = fmaxf(md, dark);
        }
        float d  = powf(md + 1e-4f, dexp);
        float nl = 1.0f / (1.0f + expf(8.0f - d * 16.0f));  // sigmoid(16d-8)
        result = dnlw * nl + (1.0f - dnlw) * d;
    } else {
        float best = -INFINITY;
        #pragma unroll
        for (int n = 0; n < NSEG; ++n) {
            float vy = s_vy[n], vx = s_vx[n];
            float wvy = s_wvy[n], wvx = s_wvx[n];
            float dy = py - vy, dx = px - vx;
            float dot = (dy * wvy + dx * wvx) * s_inv_d2[n];
            float frac = fminf(fmaxf(dot, 0.0f), 1.0f);
            float ey = dy - frac * wvy;
            float ex = dx - frac * wvx;
            float dist = sqrtf(ey * ey + ex * ex);
            float th = fmaxf(s_c0[n] + frac * s_c1[n], 1e-8f);
            float dark = fminf(fmaxf((th - dist) / th, 0.0f), 1.0f);
            float d  = powf(dark + 1e-4f, dexp);
            float nl = 1.0f / (1.0f + expf(8.0f - d * 16.0f));
            best = fmaxf(best, dnlw * nl + (1.0f - dnlw) * d);
        }
        result = best;
    }
    out[(b * H_ + i) * W_ + j] = result;
}

extern "C" void kernel_launch(void* const* d_in, const int* in_sizes, int n_in,
                              void* d_out, int out_size, void* d_ws, size_t ws_size,
                              hipStream_t stream) {
    const float* param      = (const float*)d_in[0];
    const float* x_start    = (const float*)d_in[1];
    const float* y_start    = (const float*)d_in[2];
    const float* theta      = (const float*)d_in[3];
    const float* weights    = (const float*)d_in[4];
    const float* biases     = (const float*)d_in[5];
    const float* thick_mult = (const float*)d_in[6];
    const float* thick_bias = (const float*)d_in[7];
    const float* dark_exp   = (const float*)d_in[8];
    const float* dark_nlw   = (const float*)d_in[9];
    const float* x_m        = (const float*)d_in[10];
    const float* y_m        = (const float*)d_in[11];
    const float* x_b        = (const float*)d_in[12];
    const float* y_b        = (const float*)d_in[13];
    // d_in[14] = use_conv (int), unused by the reference computation
    float* out = (float*)d_out;

    dim3 block(256);
    dim3 grid((NPIX + 255) / 256, B_);
    stroke_kernel<<<grid, block, 0, stream>>>(
        param, x_start, y_start, theta, weights, biases,
        thick_mult, thick_bias, dark_exp, dark_nlw,
        x_m, y_m, x_b, y_b, out);
}

// Round 2
// 37.278 us; speedup vs baseline: 2.2593x; 2.2593x over previous
//
#include <hip/hip_runtime.h>
#include <math.h>

#define B_ 64
#define N_ 32
#define H_ 200
#define W_ 200
#define NSEG (N_ - 1)
#define NPIX (H_ * W_)
#define HALF (NPIX / 2)   // 20000: thread handles pixel p and p+HALF (rows i, i+100)

__global__ __launch_bounds__(256) void stroke_kernel(
    const float* __restrict__ param,      // (B, N, 3)
    const float* __restrict__ x_start,    // scalar
    const float* __restrict__ y_start,    // scalar
    const float* __restrict__ theta,      // scalar
    const float* __restrict__ weights,    // (2,2)
    const float* __restrict__ biases,     // (2,)
    const float* __restrict__ thick_mult, // scalar
    const float* __restrict__ thick_bias, // scalar
    const float* __restrict__ dark_exp_p, // scalar
    const float* __restrict__ dark_nlw_p, // scalar
    const float* __restrict__ x_m_p,      // scalar
    const float* __restrict__ y_m_p,      // scalar
    const float* __restrict__ x_b_p,      // scalar
    const float* __restrict__ y_b_p,      // scalar
    float* __restrict__ out)              // (B, H, W)
{
    // Packed per-segment constants: A = (vy, vx, wvy, wvx), Bc = (inv_d2, c0, c1, _)
    __shared__ float4 s_A[NSEG];
    __shared__ float4 s_B[NSEG];
    __shared__ float s_sy[N_], s_sx[N_], s_tk[N_];

    const int b   = blockIdx.y;
    const int tid = threadIdx.x;

    const float thv  = theta[0];
    const float c    = cosf(thv), s = sinf(thv);
    const float xs   = x_start[0], ys = y_start[0];
    const float W00  = weights[0], W01 = weights[1];
    const float W10  = weights[2], W11 = weights[3];
    const float bb0  = biases[0],  bb1 = biases[1];
    const float tm   = thick_mult[0], tb = thick_bias[0];
    const float dexp = dark_exp_p[0], dnlw = dark_nlw_p[0];
    const float xm   = x_m_p[0], ym = y_m_p[0];
    const float xb   = x_b_p[0], yb = y_b_p[0];

    if (tid < N_) {
        float p0 = param[(b * N_ + tid) * 3 + 0];
        float p1 = param[(b * N_ + tid) * 3 + 1];
        float p2 = param[(b * N_ + tid) * 3 + 2];
        float x0 = p0, y0 = -p1;
        float x_rot =  x0 * c + y0 * s;
        float y_rot = -x0 * s + y0 * c;
        float yy = y_rot * ym + yb + ys;
        float xx = x_rot * xm + xb + xs;
        s_sy[tid] = yy * W00 + xx * W01 + bb0;
        s_sx[tid] = yy * W10 + xx * W11 + bb1;
        s_tk[tid] = (p2 * 2.0f + 0.5f) * (1.0f / 64.0f);
    }
    __syncthreads();

    if (tid < NSEG) {
        float vy = s_sy[tid],     vx = s_sx[tid];
        float wy = s_sy[tid + 1], wx = s_sx[tid + 1];
        float wvy = wy - vy, wvx = wx - vx;
        float d2 = wvy * wvy + wvx * wvx;
        float t0 = s_tk[tid], t1 = s_tk[tid + 1];
        s_A[tid] = make_float4(vy, vx, wvy, wvx);
        s_B[tid] = make_float4(1.0f / (d2 + 1e-5f),      // inv_d2
                               t0 * tm + tb,             // c0: th = c0 + frac*c1
                               (t1 - t0) * tm,           // c1
                               0.0f);
    }
    __syncthreads();

    const int pix = blockIdx.x * blockDim.x + tid;
    if (pix >= HALF) return;
    const int i = pix / W_;
    const int j = pix - i * W_;
    const float py0 = (float)i * (1.0f / H_);
    const float py1 = py0 + 0.5f;            // row i + 100
    const float px  = (float)j * (1.0f / W_);

    const bool hoist = (dexp > 0.0f) && (dnlw >= 0.0f) && (dnlw <= 1.0f);

    float r0, r1;
    if (hoist) {
        // max commutes with the (monotone) post-transform, and with clamp01.
        float md0 = -INFINITY, md1 = -INFINITY;
        #pragma unroll
        for (int n = 0; n < NSEG; ++n) {
            const float4 A  = s_A[n];
            const float4 Bc = s_B[n];
            const float dx   = px  - A.y;
            const float dy0  = py0 - A.x;
            const float dy1  = dy0 + 0.5f;
            const float base = dx * A.w;
            // pixel 0
            {
                float dot  = fmaf(dy0, A.z, base) * Bc.x;
                float frac = fminf(fmaxf(dot, 0.0f), 1.0f);
                float ey   = fmaf(-frac, A.z, dy0);
                float ex   = fmaf(-frac, A.w, dx);
                float e2   = fmaf(ey, ey, ex * ex);
                float dist = __builtin_amdgcn_sqrtf(e2);
                float th   = fmaxf(fmaf(frac, Bc.z, Bc.y), 1e-8f);
                float u    = fmaf(-dist, __builtin_amdgcn_rcpf(th), 1.0f);
                md0 = fmaxf(md0, u);
            }
            // pixel 1
            {
                float dot  = fmaf(dy1, A.z, base) * Bc.x;
                float frac = fminf(fmaxf(dot, 0.0f), 1.0f);
                float ey   = fmaf(-frac, A.z, dy1);
                float ex   = fmaf(-frac, A.w, dx);
                float e2   = fmaf(ey, ey, ex * ex);
                float dist = __builtin_amdgcn_sqrtf(e2);
                float th   = fmaxf(fmaf(frac, Bc.z, Bc.y), 1e-8f);
                float u    = fmaf(-dist, __builtin_amdgcn_rcpf(th), 1.0f);
                md1 = fmaxf(md1, u);
            }
        }
        {
            float md = fminf(fmaxf(md0, 0.0f), 1.0f);
            float d  = __expf(dexp * __logf(md + 1e-4f));
            float nl = __builtin_amdgcn_rcpf(1.0f + __expf(8.0f - d * 16.0f));
            r0 = dnlw * nl + (1.0f - dnlw) * d;
        }
        {
            float md = fminf(fmaxf(md1, 0.0f), 1.0f);
            float d  = __expf(dexp * __logf(md + 1e-4f));
            float nl = __builtin_amdgcn_rcpf(1.0f + __expf(8.0f - d * 16.0f));
            r1 = dnlw * nl + (1.0f - dnlw) * d;
        }
    } else {
        float b0 = -INFINITY, b1 = -INFINITY;
        #pragma unroll
        for (int n = 0; n < NSEG; ++n) {
            const float4 A  = s_A[n];
            const float4 Bc = s_B[n];
            const float dx   = px  - A.y;
            const float dy0  = py0 - A.x;
            const float dy1  = dy0 + 0.5f;
            const float base = dx * A.w;
            {
                float dot  = fmaf(dy0, A.z, base) * Bc.x;
                float frac = fminf(fmaxf(dot, 0.0f), 1.0f);
                float ey   = fmaf(-frac, A.z, dy0);
                float ex   = fmaf(-frac, A.w, dx);
                float e2   = fmaf(ey, ey, ex * ex);
                float dist = __builtin_amdgcn_sqrtf(e2);
                float th   = fmaxf(fmaf(frac, Bc.z, Bc.y), 1e-8f);
                float dark = fminf(fmaxf(fmaf(-dist, __builtin_amdgcn_rcpf(th), 1.0f), 0.0f), 1.0f);
                float d  = __expf(dexp * __logf(dark + 1e-4f));
                float nl = __builtin_amdgcn_rcpf(1.0f + __expf(8.0f - d * 16.0f));
                b0 = fmaxf(b0, dnlw * nl + (1.0f - dnlw) * d);
            }
            {
                float dot  = fmaf(dy1, A.z, base) * Bc.x;
                float frac = fminf(fmaxf(dot, 0.0f), 1.0f);
                float ey   = fmaf(-frac, A.z, dy1);
                float ex   = fmaf(-frac, A.w, dx);
                float e2   = fmaf(ey, ey, ex * ex);
                float dist = __builtin_amdgcn_sqrtf(e2);
                float th   = fmaxf(fmaf(frac, Bc.z, Bc.y), 1e-8f);
                float dark = fminf(fmaxf(fmaf(-dist, __builtin_amdgcn_rcpf(th), 1.0f), 0.0f), 1.0f);
                float d  = __expf(dexp * __logf(dark + 1e-4f));
                float nl = __builtin_amdgcn_rcpf(1.0f + __expf(8.0f - d * 16.0f));
                b1 = fmaxf(b1, dnlw * nl + (1.0f - dnlw) * d);
            }
        }
        r0 = b0; r1 = b1;
    }

    const int base_out = b * NPIX;
    out[base_out + pix]        = r0;   // row i
    out[base_out + pix + HALF] = r1;   // row i + 100
}

extern "C" void kernel_launch(void* const* d_in, const int* in_sizes, int n_in,
                              void* d_out, int out_size, void* d_ws, size_t ws_size,
                              hipStream_t stream) {
    const float* param      = (const float*)d_in[0];
    const float* x_start    = (const float*)d_in[1];
    const float* y_start    = (const float*)d_in[2];
    const float* theta      = (const float*)d_in[3];
    const float* weights    = (const float*)d_in[4];
    const float* biases     = (const float*)d_in[5];
    const float* thick_mult = (const float*)d_in[6];
    const float* thick_bias = (const float*)d_in[7];
    const float* dark_exp   = (const float*)d_in[8];
    const float* dark_nlw   = (const float*)d_in[9];
    const float* x_m        = (const float*)d_in[10];
    const float* y_m        = (const float*)d_in[11];
    const float* x_b        = (const float*)d_in[12];
    const float* y_b        = (const float*)d_in[13];
    float* out = (float*)d_out;

    dim3 block(256);
    dim3 grid((HALF + 255) / 256, B_);
    stroke_kernel<<<grid, block, 0, stream>>>(
        param, x_start, y_start, theta, weights, biases,
        thick_mult, thick_bias, dark_exp, dark_nlw,
        x_m, y_m, x_b, y_b, out);
}

// Round 3
// 16.209 us; speedup vs baseline: 5.1960x; 2.2999x over previous
//
#include <hip/hip_runtime.h>
#include <math.h>

#define B_ 64
#define N_ 32
#define H_ 200
#define W_ 200
#define NSEG (N_ - 1)
#define TS 16                 // tile side (pixels)
#define NT 13                 // ceil(200/16)
// tile half-diagonal in coord units: sqrt(2)*(7.5/200) = 0.05303 + margin
#define TILE_RAD 0.056f

__global__ __launch_bounds__(256) void stroke_kernel(
    const float* __restrict__ param,      // (B, N, 3)
    const float* __restrict__ x_start,
    const float* __restrict__ y_start,
    const float* __restrict__ theta,
    const float* __restrict__ weights,    // (2,2)
    const float* __restrict__ biases,     // (2,)
    const float* __restrict__ thick_mult,
    const float* __restrict__ thick_bias,
    const float* __restrict__ dark_exp_p,
    const float* __restrict__ dark_nlw_p,
    const float* __restrict__ x_m_p,
    const float* __restrict__ y_m_p,
    const float* __restrict__ x_b_p,
    const float* __restrict__ y_b_p,
    float* __restrict__ out)              // (B, H, W)
{
    __shared__ float4 s_A[NSEG];          // compacted: (vy, vx, wvy, wvx)
    __shared__ float4 s_B[NSEG];          // compacted: (inv_d2, c0, c1, 0)
    __shared__ float s_sy[N_], s_sx[N_], s_tk[N_];
    __shared__ int s_cnt;

    const int b   = blockIdx.z;
    const int tid = threadIdx.x;

    const float thv  = theta[0];
    const float c    = cosf(thv), s = sinf(thv);
    const float xs   = x_start[0], ys = y_start[0];
    const float W00  = weights[0], W01 = weights[1];
    const float W10  = weights[2], W11 = weights[3];
    const float bb0  = biases[0],  bb1 = biases[1];
    const float tm   = thick_mult[0], tb = thick_bias[0];
    const float dexp = dark_exp_p[0], dnlw = dark_nlw_p[0];
    const float xm   = x_m_p[0], ym = y_m_p[0];
    const float xb   = x_b_p[0], yb = y_b_p[0];

    // Phase 1: strokes + thickness into LDS
    if (tid < N_) {
        float p0 = param[(b * N_ + tid) * 3 + 0];
        float p1 = param[(b * N_ + tid) * 3 + 1];
        float p2 = param[(b * N_ + tid) * 3 + 2];
        float x0 = p0, y0 = -p1;
        float x_rot =  x0 * c + y0 * s;
        float y_rot = -x0 * s + y0 * c;
        float yy = y_rot * ym + yb + ys;
        float xx = x_rot * xm + xb + xs;
        s_sy[tid] = yy * W00 + xx * W01 + bb0;
        s_sx[tid] = yy * W10 + xx * W11 + bb1;
        s_tk[tid] = (p2 * 2.0f + 0.5f) * (1.0f / 64.0f);
    }
    __syncthreads();

    // Phase 2: per-segment constants + conservative tile cull + ballot-compact
    const float cy = ((float)(blockIdx.y * TS) + 7.5f) * (1.0f / H_);
    const float cx = ((float)(blockIdx.x * TS) + 7.5f) * (1.0f / W_);

    bool keep = false;
    float4 A4, B4;
    if (tid < NSEG) {
        float vy = s_sy[tid],     vx = s_sx[tid];
        float wy = s_sy[tid + 1], wx = s_sx[tid + 1];
        float wvy = wy - vy, wvx = wx - vx;
        float d2 = wvy * wvy + wvx * wvx;
        float inv_d2 = 1.0f / (d2 + 1e-5f);
        float t0 = s_tk[tid], t1 = s_tk[tid + 1];
        float c0 = t0 * tm + tb;          // th(frac) = c0 + frac*c1 (pre-clamp)
        float c1 = (t1 - t0) * tm;
        A4 = make_float4(vy, vx, wvy, wvx);
        B4 = make_float4(inv_d2, c0, c1, 0.0f);
        // point(tile center)-to-segment distance
        float dyc = cy - vy, dxc = cx - vx;
        float dot = (dyc * wvy + dxc * wvx) * inv_d2;
        float fr  = fminf(fmaxf(dot, 0.0f), 1.0f);
        float ey  = dyc - fr * wvy;
        float ex  = dxc - fr * wvx;
        float e2c = ey * ey + ex * ex;
        // max thickness over frac in [0,1], incl. the 1e-8 clamp
        float thmax = fmaxf(fmaxf(c0, c0 + c1), 1e-8f);
        float reach = thmax + TILE_RAD;   // dist >= th everywhere -> dark = 0
        keep = e2c < reach * reach;
    }
    if (tid < 64) {   // ballot-compact within wave 0 (segments all live there)
        unsigned long long mask = __ballot(keep);
        int pos = (int)__popcll(mask & ((1ull << tid) - 1ull));
        if (keep) { s_A[pos] = A4; s_B[pos] = B4; }
        if (tid == 0) s_cnt = (int)__popcll(mask);
    }
    __syncthreads();

    const int cnt = s_cnt;
    const int ii = tid >> 4, jj = tid & 15;
    const int i = blockIdx.y * TS + ii;
    const int j = blockIdx.x * TS + jj;
    const float py = (float)i * (1.0f / H_);
    const float px = (float)j * (1.0f / W_);

    const bool hoist = (dexp > 0.0f) && (dnlw >= 0.0f) && (dnlw <= 1.0f);

    float result;
    if (hoist) {
        // maximize dark = 1 - sqrt(e2)/th  <=>  minimize q = e2 * rcp(th)^2.
        // sqrt deferred to once per pixel; clamp01 once at the end subsumes
        // the per-segment clamp (monotone) and the culled segments' zeros.
        float qmin = INFINITY;
        if (cnt > 0) {
            float4 A = s_A[0], Bc = s_B[0];
            for (int n = 0; n < cnt; ++n) {
                int np = (n + 1 < cnt) ? n + 1 : n;     // prefetch next
                float4 An = s_A[np], Bn = s_B[np];
                float dy  = py - A.x;
                float dx  = px - A.y;
                float dot = fmaf(dy, A.z, dx * A.w) * Bc.x;
                float fr  = fminf(fmaxf(dot, 0.0f), 1.0f);
                float ey  = fmaf(-fr, A.z, dy);
                float ex  = fmaf(-fr, A.w, dx);
                float e2  = fmaf(ey, ey, ex * ex);
                float th  = fmaxf(fmaf(fr, Bc.z, Bc.y), 1e-8f);
                float ith = __builtin_amdgcn_rcpf(th);
                float q   = (e2 * ith) * ith;
                qmin = fminf(qmin, q);
                A = An; Bc = Bn;
            }
        }
        float md = fminf(fmaxf(1.0f - __builtin_amdgcn_sqrtf(qmin), 0.0f), 1.0f);
        float d  = __expf(dexp * __logf(md + 1e-4f));
        float nl = __builtin_amdgcn_rcpf(1.0f + __expf(8.0f - d * 16.0f));
        result = dnlw * nl + (1.0f - dnlw) * d;
    } else {
        // generic fallback: per-segment transform; culled segments contribute
        // T(0) — include it only if something was actually culled.
        float best = -INFINITY;
        if (cnt < NSEG) {
            float d0  = __expf(dexp * __logf(1e-4f));
            float nl0 = __builtin_amdgcn_rcpf(1.0f + __expf(8.0f - d0 * 16.0f));
            best = dnlw * nl0 + (1.0f - dnlw) * d0;
        }
        for (int n = 0; n < cnt; ++n) {
            float4 A = s_A[n], Bc = s_B[n];
            float dy  = py - A.x;
            float dx  = px - A.y;
            float dot = fmaf(dy, A.z, dx * A.w) * Bc.x;
            float fr  = fminf(fmaxf(dot, 0.0f), 1.0f);
            float ey  = fmaf(-fr, A.z, dy);
            float ex  = fmaf(-fr, A.w, dx);
            float e2  = fmaf(ey, ey, ex * ex);
            float dist = __builtin_amdgcn_sqrtf(e2);
            float th  = fmaxf(fmaf(fr, Bc.z, Bc.y), 1e-8f);
            float dark = fminf(fmaxf(fmaf(-dist, __builtin_amdgcn_rcpf(th), 1.0f), 0.0f), 1.0f);
            float d  = __expf(dexp * __logf(dark + 1e-4f));
            float nl = __builtin_amdgcn_rcpf(1.0f + __expf(8.0f - d * 16.0f));
            best = fmaxf(best, dnlw * nl + (1.0f - dnlw) * d);
        }
        result = best;
    }

    if (i < H_ && j < W_)
        out[(b * H_ + i) * W_ + j] = result;
}

extern "C" void kernel_launch(void* const* d_in, const int* in_sizes, int n_in,
                              void* d_out, int out_size, void* d_ws, size_t ws_size,
                              hipStream_t stream) {
    const float* param      = (const float*)d_in[0];
    const float* x_start    = (const float*)d_in[1];
    const float* y_start    = (const float*)d_in[2];
    const float* theta      = (const float*)d_in[3];
    const float* weights    = (const float*)d_in[4];
    const float* biases     = (const float*)d_in[5];
    const float* thick_mult = (const float*)d_in[6];
    const float* thick_bias = (const float*)d_in[7];
    const float* dark_exp   = (const float*)d_in[8];
    const float* dark_nlw   = (const float*)d_in[9];
    const float* x_m        = (const float*)d_in[10];
    const float* y_m        = (const float*)d_in[11];
    const float* x_b        = (const float*)d_in[12];
    const float* y_b        = (const float*)d_in[13];
    float* out = (float*)d_out;

    dim3 block(256);
    dim3 grid(NT, NT, B_);
    stroke_kernel<<<grid, block, 0, stream>>>(
        param, x_start, y_start, theta, weights, biases,
        thick_mult, thick_bias, dark_exp, dark_nlw,
        x_m, y_m, x_b, y_b, out);
}

// Round 4
// 14.367 us; speedup vs baseline: 5.8622x; 1.1282x over previous
//
#include <hip/hip_runtime.h>
#include <math.h>

#define B_ 64
#define N_ 32
#define H_ 200
#define W_ 200
#define NSEG (N_ - 1)
#define TSX 32                // tile width (pixels), 2 px/thread in x
#define TSY 16                // tile height
#define NTX 7                 // ceil(200/32)
#define NTY 13                // ceil(200/16)
// tile half-diagonal: sqrt((15.5/200)^2 + (7.5/200)^2) = 0.0861 + margin
#define TILE_RAD 0.087f

__global__ __launch_bounds__(256) void stroke_kernel(
    const float* __restrict__ param,      // (B, N, 3)
    const float* __restrict__ x_start,
    const float* __restrict__ y_start,
    const float* __restrict__ theta,
    const float* __restrict__ weights,    // (2,2)
    const float* __restrict__ biases,     // (2,)
    const float* __restrict__ thick_mult,
    const float* __restrict__ thick_bias,
    const float* __restrict__ dark_exp_p,
    const float* __restrict__ dark_nlw_p,
    const float* __restrict__ x_m_p,
    const float* __restrict__ y_m_p,
    const float* __restrict__ x_b_p,
    const float* __restrict__ y_b_p,
    float* __restrict__ out)              // (B, H, W)
{
    __shared__ float4 s_A[NSEG];   // compacted: (vy, vx, wvy, wvx)
    __shared__ float4 s_B[NSEG];   // compacted: (inv_d2, c0, c1, ddot = wvx*inv_d2/W)
    __shared__ int s_cnt;

    const int b   = blockIdx.z;
    const int tid = threadIdx.x;

    // needed by every thread for the epilogue (uniform s_loads)
    const float dexp = dark_exp_p[0], dnlw = dark_nlw_p[0];

    // ---- Wave-0-only setup: endpoints in registers, shfl neighbors, cull,
    // ---- ballot-compact. Waves 1-3 go straight to the barrier.
    if (tid < 64) {
        float sy = 0.0f, sx = 0.0f, tk = 0.0f;
        const float tm = thick_mult[0], tb = thick_bias[0];
        if (tid < N_) {
            const float thv = theta[0];
            const float c   = cosf(thv), s = sinf(thv);
            const float xs  = x_start[0], ys = y_start[0];
            const float W00 = weights[0], W01 = weights[1];
            const float W10 = weights[2], W11 = weights[3];
            const float bb0 = biases[0],  bb1 = biases[1];
            const float xm  = x_m_p[0], ym = y_m_p[0];
            const float xb  = x_b_p[0], yb = y_b_p[0];
            float p0 = param[(b * N_ + tid) * 3 + 0];
            float p1 = param[(b * N_ + tid) * 3 + 1];
            float p2 = param[(b * N_ + tid) * 3 + 2];
            float x0 = p0, y0 = -p1;
            float x_rot =  x0 * c + y0 * s;
            float y_rot = -x0 * s + y0 * c;
            float yy = y_rot * ym + yb + ys;
            float xx = x_rot * xm + xb + xs;
            sy = yy * W00 + xx * W01 + bb0;
            sx = yy * W10 + xx * W11 + bb1;
            tk = (p2 * 2.0f + 0.5f) * (1.0f / 64.0f);
        }
        // neighbor endpoint via wave shuffle (no LDS, no extra barrier)
        float sy1 = __shfl_down(sy, 1);
        float sx1 = __shfl_down(sx, 1);
        float tk1 = __shfl_down(tk, 1);

        bool keep = false;
        float4 A4 = make_float4(0,0,0,0), B4 = make_float4(0,0,0,0);
        if (tid < NSEG) {
            float wvy = sy1 - sy, wvx = sx1 - sx;
            float d2 = wvy * wvy + wvx * wvx;
            float inv_d2 = 1.0f / (d2 + 1e-5f);
            float c0 = tk * tm + tb;            // th(frac) = c0 + frac*c1
            float c1 = (tk1 - tk) * tm;
            A4 = make_float4(sy, sx, wvy, wvx);
            B4 = make_float4(inv_d2, c0, c1, wvx * inv_d2 * (1.0f / W_));
            // conservative tile cull (circle around tile center)
            const float cy = ((float)(blockIdx.y * TSY) + 7.5f)  * (1.0f / H_);
            const float cx = ((float)(blockIdx.x * TSX) + 15.5f) * (1.0f / W_);
            float dyc = cy - sy, dxc = cx - sx;
            float dot = (dyc * wvy + dxc * wvx) * inv_d2;
            float fr  = fminf(fmaxf(dot, 0.0f), 1.0f);
            float ey  = dyc - fr * wvy;
            float ex  = dxc - fr * wvx;
            float e2c = ey * ey + ex * ex;
            float thmax = fmaxf(fmaxf(c0, c0 + c1), 1e-8f);
            float reach = thmax + TILE_RAD;     // beyond -> dark==0 everywhere in tile
            keep = e2c < reach * reach;
        }
        unsigned long long mask = __ballot(keep);
        int pos = (int)__popcll(mask & ((1ull << tid) - 1ull));
        if (keep) { s_A[pos] = A4; s_B[pos] = B4; }
        if (tid == 0) s_cnt = (int)__popcll(mask);
    }
    __syncthreads();

    const int cnt = s_cnt;
    const int ii = tid >> 4, jj = tid & 15;
    const int i  = blockIdx.y * TSY + ii;
    const int j0 = blockIdx.x * TSX + (jj << 1);       // even -> float2-aligned
    const float py  = (float)i  * (1.0f / H_);
    const float px0 = (float)j0 * (1.0f / W_);
    const float px1 = px0 + (1.0f / W_);

    const bool hoist = (dexp > 0.0f) && (dnlw >= 0.0f) && (dnlw <= 1.0f);

    float r0, r1;
    if (hoist) {
        // maximize dark = 1 - sqrt(e2)/th  <=>  minimize q = e2*rcp(th)^2;
        // sqrt once per pixel; final clamp01 subsumes per-seg clamp + culled zeros.
        float q0m = INFINITY, q1m = INFINITY;
        if (cnt > 0) {
            float4 A = s_A[0], Bc = s_B[0];
            for (int n = 0; n < cnt; ++n) {
                int np = (n + 1 < cnt) ? n + 1 : n;    // prefetch next
                float4 An = s_A[np], Bn = s_B[np];
                float dy  = py  - A.x;
                float dx0 = px0 - A.y;
                float dx1 = px1 - A.y;
                float dot0 = fmaf(dy, A.z, dx0 * A.w) * Bc.x;
                float dot1 = dot0 + Bc.w;              // += step*wvx*inv_d2
                float fr0 = __builtin_amdgcn_fmed3f(dot0, 0.0f, 1.0f);
                float fr1 = __builtin_amdgcn_fmed3f(dot1, 0.0f, 1.0f);
                float ey0 = fmaf(-fr0, A.z, dy);
                float ex0 = fmaf(-fr0, A.w, dx0);
                float e20 = fmaf(ey0, ey0, ex0 * ex0);
                float th0 = fmaxf(fmaf(fr0, Bc.z, Bc.y), 1e-8f);
                float it0 = __builtin_amdgcn_rcpf(th0);
                q0m = fminf(q0m, (e20 * it0) * it0);
                float ey1 = fmaf(-fr1, A.z, dy);
                float ex1 = fmaf(-fr1, A.w, dx1);
                float e21 = fmaf(ey1, ey1, ex1 * ex1);
                float th1 = fmaxf(fmaf(fr1, Bc.z, Bc.y), 1e-8f);
                float it1 = __builtin_amdgcn_rcpf(th1);
                q1m = fminf(q1m, (e21 * it1) * it1);
                A = An; Bc = Bn;
            }
        }
        {
            float md = fminf(fmaxf(1.0f - __builtin_amdgcn_sqrtf(q0m), 0.0f), 1.0f);
            float d  = __expf(dexp * __logf(md + 1e-4f));
            float nl = __builtin_amdgcn_rcpf(1.0f + __expf(8.0f - d * 16.0f));
            r0 = dnlw * nl + (1.0f - dnlw) * d;
        }
        {
            float md = fminf(fmaxf(1.0f - __builtin_amdgcn_sqrtf(q1m), 0.0f), 1.0f);
            float d  = __expf(dexp * __logf(md + 1e-4f));
            float nl = __builtin_amdgcn_rcpf(1.0f + __expf(8.0f - d * 16.0f));
            r1 = dnlw * nl + (1.0f - dnlw) * d;
        }
    } else {
        // generic fallback: per-segment transform; culled segments contribute
        // T(0) — include it only if something was actually culled.
        float b0 = -INFINITY, b1 = -INFINITY;
        if (cnt < NSEG) {
            float d0  = __expf(dexp * __logf(1e-4f));
            float nl0 = __builtin_amdgcn_rcpf(1.0f + __expf(8.0f - d0 * 16.0f));
            float t0  = dnlw * nl0 + (1.0f - dnlw) * d0;
            b0 = t0; b1 = t0;
        }
        for (int n = 0; n < cnt; ++n) {
            float4 A = s_A[n], Bc = s_B[n];
            float dy  = py  - A.x;
            float dx0 = px0 - A.y;
            float dx1 = px1 - A.y;
            float dot0 = fmaf(dy, A.z, dx0 * A.w) * Bc.x;
            float dot1 = dot0 + Bc.w;
            float fr0 = __builtin_amdgcn_fmed3f(dot0, 0.0f, 1.0f);
            float fr1 = __builtin_amdgcn_fmed3f(dot1, 0.0f, 1.0f);
            {
                float ey = fmaf(-fr0, A.z, dy);
                float ex = fmaf(-fr0, A.w, dx0);
                float dist = __builtin_amdgcn_sqrtf(fmaf(ey, ey, ex * ex));
                float th = fmaxf(fmaf(fr0, Bc.z, Bc.y), 1e-8f);
                float dark = fminf(fmaxf(fmaf(-dist, __builtin_amdgcn_rcpf(th), 1.0f), 0.0f), 1.0f);
                float d  = __expf(dexp * __logf(dark + 1e-4f));
                float nl = __builtin_amdgcn_rcpf(1.0f + __expf(8.0f - d * 16.0f));
                b0 = fmaxf(b0, dnlw * nl + (1.0f - dnlw) * d);
            }
            {
                float ey = fmaf(-fr1, A.z, dy);
                float ex = fmaf(-fr1, A.w, dx1);
                float dist = __builtin_amdgcn_sqrtf(fmaf(ey, ey, ex * ex));
                float th = fmaxf(fmaf(fr1, Bc.z, Bc.y), 1e-8f);
                float dark = fminf(fmaxf(fmaf(-dist, __builtin_amdgcn_rcpf(th), 1.0f), 0.0f), 1.0f);
                float d  = __expf(dexp * __logf(dark + 1e-4f));
                float nl = __builtin_amdgcn_rcpf(1.0f + __expf(8.0f - d * 16.0f));
                b1 = fmaxf(b1, dnlw * nl + (1.0f - dnlw) * d);
            }
        }
        r0 = b0; r1 = b1;
    }

    if (i < H_ && j0 < W_) {   // W even, j0 even -> pair never straddles edge
        *reinterpret_cast<float2*>(&out[(b * H_ + i) * W_ + j0]) = make_float2(r0, r1);
    }
}

extern "C" void kernel_launch(void* const* d_in, const int* in_sizes, int n_in,
                              void* d_out, int out_size, void* d_ws, size_t ws_size,
                              hipStream_t stream) {
    const float* param      = (const float*)d_in[0];
    const float* x_start    = (const float*)d_in[1];
    const float* y_start    = (const float*)d_in[2];
    const float* theta      = (const float*)d_in[3];
    const float* weights    = (const float*)d_in[4];
    const float* biases     = (const float*)d_in[5];
    const float* thick_mult = (const float*)d_in[6];
    const float* thick_bias = (const float*)d_in[7];
    const float* dark_exp   = (const float*)d_in[8];
    const float* dark_nlw   = (const float*)d_in[9];
    const float* x_m        = (const float*)d_in[10];
    const float* y_m        = (const float*)d_in[11];
    const float* x_b        = (const float*)d_in[12];
    const float* y_b        = (const float*)d_in[13];
    float* out = (float*)d_out;

    dim3 block(256);
    dim3 grid(NTX, NTY, B_);
    stroke_kernel<<<grid, block, 0, stream>>>(
        param, x_start, y_start, theta, weights, biases,
        thick_mult, thick_bias, dark_exp, dark_nlw,
        x_m, y_m, x_b, y_b, out);
}